// Round 8
// baseline (250.950 us; speedup 1.0000x reference)
//
#include <hip/hip_runtime.h>
#include <hip/hip_bf16.h>
#include <stdint.h>

namespace {
constexpr int kB = 8, kT = 16, kN = 1000, kF = 16;
constexpr int kE = 16000;
constexpr int kH = 4, kHD = 128;
constexpr int kHL = 64, kOUT = 8;
constexpr int kG = kB * kT;
constexpr float kNeg = 0.2f;

// Canonical bf16 weights (for lstm_head + bg), element offsets:
constexpr size_t CX_WG   = 0;                       // 2048 (layout only)
constexpr size_t CX_ATS  = CX_WG   + 2048;
constexpr size_t CX_ATD  = CX_ATS  + 128;
constexpr size_t CX_BG   = CX_ATD  + 128;
constexpr size_t CX_WIH  = CX_BG   + 128;
constexpr size_t CX_WHH  = CX_WIH  + 32768;
constexpr size_t CX_BIH  = CX_WHH  + 16384;
constexpr size_t CX_BHH  = CX_BIH  + 256;
constexpr size_t CX_WCLF = CX_BHH  + 256;
constexpr size_t CX_BCLF = CX_WCLF + 512;
constexpr size_t CX_TOTAL = CX_BCLF + 8;

// Workspace byte offsets (256-aligned)
constexpr size_t OFF_FLAG  = 0;
constexpr size_t OFF_ROW   = 256;
constexpr size_t OFF_COL   = 4352;
constexpr size_t OFF_POOL  = 68608;                  // float[kG*kHD]
constexpr size_t OFF_CANON = 134400;                 // bf16[CX_TOTAL]
constexpr size_t OFF_AS    = 239872;
// a_s: 128*16000 B, a_d: 128*16000 B, xp(bf16): 128*256000 B  (~37 MB total)

constexpr int kSetupBlocks = 10;   // 0: CSR, 1..8: convert, 9: pooled zero
}

__device__ __forceinline__ float bf2f(unsigned short u) {
    return __uint_as_float(((uint32_t)u) << 16);
}
__device__ __forceinline__ float blo(uint32_t u) { return __uint_as_float(u << 16); }
__device__ __forceinline__ unsigned short f2bf(float f) {
    uint32_t u = __float_as_uint(f);
    uint32_t r = (u + 0x7fff + ((u >> 16) & 1)) >> 16;
    return (unsigned short)r;
}
__device__ __forceinline__ float sigm(float x) { return 1.f / (1.f + __expf(-x)); }

// dtype probe: bf16 N(0,1) shorts are ~100% in exponent band [97,143];
// fp32 viewed as shorts ~59%. Returns 1 if tensors are fp32.
__device__ __forceinline__ int detect_isf(const unsigned short* xs, int t,
                                          int nthr, int* sh_cnt) {
    if (t == 0) *sh_cnt = 0;
    __syncthreads();
    int loc = 0;
    for (int i = t; i < 2048; i += nthr) {
        unsigned short u = xs[i];
        int ex = (u >> 7) & 0xff;
        if (u == 0 || (ex >= 97 && ex <= 143)) loc++;
    }
    atomicAdd(sh_cnt, loc);
    __syncthreads();
    return (*sh_cnt >= (2048 * 8) / 10) ? 0 : 1;
}

struct ConvArgs {
    const unsigned short* src[10];
    int n[10];
};

// ---------------------------------------------------------------------------
// Kernel 1 (mega-setup, 10+2048 blocks x 256):
//  block 0:    CSR build (dst-sorted edges), wave-scan
//  blocks 1-8: convert weights to canonical bf16 (8-way split, no straggler)
//  block 9:    zero pooled
//  blocks 10+: xp = x @ W_gat (packed-uint stores) + a_s/a_d via folded
//              weights (lane-rotated d-loop: conflict-free). Graph-major XCD
//              swizzle (matches gat_aggregate -> L2 temporal locality).
// ---------------------------------------------------------------------------
__global__ __launch_bounds__(256) void mega_setup(
        const void* __restrict__ xraw, const int* __restrict__ ei,
        ConvArgs ca,
        const unsigned short* __restrict__ WgR,
        const unsigned short* __restrict__ atsR,
        const unsigned short* __restrict__ atdR,
        int* __restrict__ flag, int* __restrict__ row, int* __restrict__ col,
        unsigned short* __restrict__ canon,
        unsigned short* __restrict__ xp_all,
        float* __restrict__ as_all, float* __restrict__ ad_all,
        unsigned int* __restrict__ pooled) {
    const int t = threadIdx.x;
    const unsigned short* xs = (const unsigned short*)xraw;

    if (blockIdx.x == 0) {
        // ================= CSR build =================
        __shared__ int cnt[1024];
        __shared__ int wtot[4];
        const int lane = t & 63, w = t >> 6;
        for (int i = t; i < 1024; i += 256) cnt[i] = 0;
        __syncthreads();
        const int* dst = ei + kE;
        for (int e = t; e < kE; e += 256) atomicAdd(&cnt[dst[e]], 1);
        __syncthreads();
        const int n0 = 4 * t;
        int c0 = cnt[n0], c1 = cnt[n0 + 1], c2 = cnt[n0 + 2], c3 = cnt[n0 + 3];
        int s0 = c0, s1 = s0 + c1, s2 = s1 + c2, s3 = s2 + c3;
        int tot = s3;
#pragma unroll
        for (int sft = 1; sft < 64; sft <<= 1) {
            int v = __shfl_up(tot, sft, 64);
            if (lane >= sft) tot += v;
        }
        if (lane == 63) wtot[w] = tot;
        __syncthreads();
        int wexcl = 0;
        for (int j = 0; j < w; ++j) wexcl += wtot[j];
        const int excl = wexcl + tot - s3;
        if (t == 0) row[0] = 0;
        if (n0 < kN) {
            row[n0 + 1] = excl + s0;
            row[n0 + 2] = excl + s1;
            row[n0 + 3] = excl + s2;
            row[n0 + 4] = excl + s3;
        }
        __syncthreads();
        cnt[n0] = excl; cnt[n0 + 1] = excl + s0;
        cnt[n0 + 2] = excl + s1; cnt[n0 + 3] = excl + s2;
        __syncthreads();
        for (int e = t; e < kE; e += 256) {
            int d0 = dst[e];
            int pos = atomicAdd(&cnt[d0], 1);
            col[pos] = ei[e];
        }
    } else if (blockIdx.x <= 8) {
        // ================= weight conversion (8-way split) =================
        __shared__ int dcnt;
        const int isf = detect_isf(xs, t, 256, &dcnt);
        if (blockIdx.x == 1 && t == 0) *flag = isf;
        const int gid = (int)(blockIdx.x - 1) * 256 + t;   // 0..2047
        size_t base = 0;
        for (int s = 0; s < 10; ++s) {
            const int n = ca.n[s];
            if (isf) {
                const float* fp = (const float*)ca.src[s];
                for (int i = gid; i < n; i += 2048) canon[base + i] = f2bf(fp[i]);
            } else {
                const unsigned short* sp = ca.src[s];
                for (int i = gid; i < n; i += 2048) canon[base + i] = sp[i];
            }
            base += (size_t)n;
        }
    } else if (blockIdx.x == 9) {
        for (int i = t; i < kG * kHD; i += 256) pooled[i] = 0u;
    } else {
        // ================= precompute tile =================
        __shared__ int dcnt;
        __shared__ float Wl[kF * kHD];
        __shared__ float asl[kHD], adl[kHD];
        __shared__ float xr[64][20];        // stride 20: conflict-free + aligned
        __shared__ float ws2[2][4][16];     // folded att weights [src/dst][h][f]
        const int isf = detect_isf(xs, t, 256, &dcnt);
        // graph-major XCD swizzle: XCD v handles graphs v, v+8, ... sequentially
        const int i0 = blockIdx.x - kSetupBlocks;
        const int v = i0 & 7;
        const int jj = i0 >> 3;             // 0..255
        const int gl = v + 8 * (jj >> 4);
        const int nb = jj & 15;
        if (isf) {
            const float* wf = (const float*)WgR;
            for (int i = t; i < kF * kHD; i += 256) Wl[i] = wf[i];
            if (t < kHD) asl[t] = ((const float*)atsR)[t];
            else if (t < 2 * kHD) adl[t - kHD] = ((const float*)atdR)[t - kHD];
        } else {
            for (int i = t; i < kF * kHD; i += 256) Wl[i] = bf2f(WgR[i]);
            if (t < kHD) asl[t] = bf2f(atsR[t]);
            else if (t < 2 * kHD) adl[t - kHD] = bf2f(atdR[t - kHD]);
        }
        const int n0 = nb * 64;
        const int nn = min(64, kN - n0);
        const size_t xbase = (size_t)gl * kN * kF + (size_t)n0 * kF;
        if (isf) {
            const float* xf = (const float*)xraw;
            for (int i = t; i < nn * kF; i += 256) xr[i >> 4][i & 15] = xf[xbase + i];
        } else {
            for (int i = t; i < nn * kF; i += 256) xr[i >> 4][i & 15] = bf2f(xs[xbase + i]);
        }
        __syncthreads();

        // folded weights ws2[sd][h][f] = sum_d Wl[f][h*32+d]*att[h*32+d];
        // d-loop rotated by lane -> banks spread, 2-way max (free).
        if (t < 128) {
            const int sd = t >> 6, h = (t >> 4) & 3, f = t & 15;
            const float* att = sd ? adl : asl;
            const int d0r = t & 31;
            float acc = 0.f;
#pragma unroll
            for (int i = 0; i < 32; ++i) {
                const int d = (d0r + i) & 31;
                acc += Wl[f * kHD + h * 32 + d] * att[h * 32 + d];
            }
            ws2[sd][h][f] = acc;
        }

        // xp tile: wave q owns node ln=q,q+4,..; lane p owns channel pair 2p.
        // Packed uint store: 4 B/lane coalesced (256 B per wave-store).
        uint32_t* xp32 = (uint32_t*)(xp_all + (size_t)gl * kN * kHD);
        {
            const int p = t & 63;
            const int q = t >> 6;
            const int c0 = 2 * p;
            float wA[kF], wB[kF];
#pragma unroll
            for (int f = 0; f < kF; ++f) {
                wA[f] = Wl[f * kHD + c0];
                wB[f] = Wl[f * kHD + c0 + 1];
            }
            for (int ln = q; ln < nn; ln += 4) {
                const float4* xrv = (const float4*)xr[ln];
                const float4 x0 = xrv[0], x1 = xrv[1], x2 = xrv[2], x3 = xrv[3];
                float vA = x0.x * wA[0]  + x0.y * wA[1]  + x0.z * wA[2]  + x0.w * wA[3]
                         + x1.x * wA[4]  + x1.y * wA[5]  + x1.z * wA[6]  + x1.w * wA[7]
                         + x2.x * wA[8]  + x2.y * wA[9]  + x2.z * wA[10] + x2.w * wA[11]
                         + x3.x * wA[12] + x3.y * wA[13] + x3.z * wA[14] + x3.w * wA[15];
                float vB = x0.x * wB[0]  + x0.y * wB[1]  + x0.z * wB[2]  + x0.w * wB[3]
                         + x1.x * wB[4]  + x1.y * wB[5]  + x1.z * wB[6]  + x1.w * wB[7]
                         + x2.x * wB[8]  + x2.y * wB[9]  + x2.z * wB[10] + x2.w * wB[11]
                         + x3.x * wB[12] + x3.y * wB[13] + x3.z * wB[14] + x3.w * wB[15];
                const uint32_t pk = (uint32_t)f2bf(vA) | ((uint32_t)f2bf(vB) << 16);
                xp32[(size_t)(n0 + ln) * 64 + p] = pk;
            }
        }
        __syncthreads();

        // a_s/a_d: thread t -> (node n=t>>2, head h=t&3); 16-MAC dots via ws2
        {
            const int n = t >> 2, h = t & 3;
            if (n < nn) {
                const float* xv = xr[n];
                const float* wsv = ws2[0][h];
                const float* wdv = ws2[1][h];
                float accS = 0.f, accD = 0.f;
#pragma unroll
                for (int f = 0; f < kF; ++f) {
                    const float xf = xv[f];
                    accS += xf * wsv[f];
                    accD += xf * wdv[f];
                }
                as_all[((size_t)gl * kN + n0 + n) * kH + h] = accS;
                ad_all[((size_t)gl * kN + n0 + n) * kH + h] = accD;
            }
        }
    }
}

// ---------------------------------------------------------------------------
// Kernel 2: GAT edge-softmax aggregation + relu + max-pool.
// One block = 20 nodes of ONE graph (5 iters x 4 waves) -> kG*50 blocks for
// latency hiding. Graph-major XCD swizzle (matches mega_setup).
// No softmax max-subtraction (logits small; exp safe in fp32).
// Phase 1: lanes = edges -> exp(leakyrelu) to SoA LDS, padded to x4.
// Phase 2: 4 edge-subgroups x 16 lanes; lane loads dwordx4 = 8 channels;
//          odd channels use raw dword as f32 (hi-bf16 + eps mantissa).
// ---------------------------------------------------------------------------
__global__ __launch_bounds__(256) void gat_aggregate(
        const int* __restrict__ row, const int* __restrict__ col,
        const unsigned short* __restrict__ xp,
        const float* __restrict__ a_s, const float* __restrict__ a_d,
        const unsigned short* __restrict__ bg,
        unsigned int* __restrict__ pooled) {
    __shared__ int   col_lds[4][64];
    __shared__ float p_lds[4][4][72];
    __shared__ float pm[4][kHD];

    const int w = threadIdx.x >> 6;
    const int lane = threadIdx.x & 63;
    const int sub = lane >> 4;          // edge subgroup 0..3
    const int cl = lane & 15;           // channels cl*8 .. cl*8+7
    const int hh = cl >> 2;
    const int xcd = blockIdx.x & 7;
    const int j = blockIdx.x >> 3;      // 0..799
    const int gl = xcd + 8 * (j / 50);  // graph-major within XCD
    const int blk = j % 50;             // 0..49
    const size_t gn = (size_t)gl * kN;
    const char* xpcl = (const char*)(xp + gn * kHD) + cl * 16;
    const float4* as4 = (const float4*)a_s + gn;
    const float4* ad4 = (const float4*)a_d + gn;
    const uint32_t* bg32 = (const uint32_t*)bg;
    float bgv[8];
#pragma unroll
    for (int jb = 0; jb < 4; ++jb) {
        uint32_t u = bg32[cl * 4 + jb];
        bgv[2 * jb] = blo(u);
        bgv[2 * jb + 1] = __uint_as_float(u & 0xffff0000u);
    }
    float pool[8];
#pragma unroll
    for (int jb = 0; jb < 8; ++jb) pool[jb] = 0.f;

    for (int it = 0; it < 5; ++it) {
        const int n = blk * 20 + it * 4 + w;
        const int r0 = row[n];
        const int deg = row[n + 1] - r0;
        const int E = deg + 1;          // + self loop (index deg)
        const float4 dv = ad4[n];
        float acc[8];
#pragma unroll
        for (int jb = 0; jb < 8; ++jb) acc[jb] = 0.f;
        float dh = 0.f;

        for (int base = 0; base < E; base += 64) {
            const int cnt = min(64, E - base);
            const int cntP = (cnt + 3) & ~3;
            // ---- phase 1: lanes = edges (pad lanes get alpha 0) ----
            if (lane < cntP) {
                const int eg = base + lane;
                const bool act = lane < cnt;
                const int s = (act && eg < deg) ? col[r0 + eg] : n;
                float p0 = 0.f, p1 = 0.f, p2 = 0.f, p3 = 0.f;
                if (act) {
                    const float4 av = as4[s];
                    float t0 = av.x + dv.x, t1 = av.y + dv.y;
                    float t2 = av.z + dv.z, t3 = av.w + dv.w;
                    t0 = t0 > 0.f ? t0 : kNeg * t0;
                    t1 = t1 > 0.f ? t1 : kNeg * t1;
                    t2 = t2 > 0.f ? t2 : kNeg * t2;
                    t3 = t3 > 0.f ? t3 : kNeg * t3;
                    p0 = __expf(t0); p1 = __expf(t1);
                    p2 = __expf(t2); p3 = __expf(t3);
                }
                col_lds[w][lane] = s << 8;          // xp row byte offset
                p_lds[w][0][lane] = p0;
                p_lds[w][1][lane] = p1;
                p_lds[w][2][lane] = p2;
                p_lds[w][3][lane] = p3;
            }
            // wave-synchronous LDS use; branch-free inner loop
            for (int e0 = 0; e0 < cntP; e0 += 4) {
                const int e = e0 + sub;
                const int off = col_lds[w][e];
                const float al = p_lds[w][hh][e];
                const uint4 u = *(const uint4*)(xpcl + off);
                acc[0] += al * blo(u.x); acc[1] += al * __uint_as_float(u.x);
                acc[2] += al * blo(u.y); acc[3] += al * __uint_as_float(u.y);
                acc[4] += al * blo(u.z); acc[5] += al * __uint_as_float(u.z);
                acc[6] += al * blo(u.w); acc[7] += al * __uint_as_float(u.w);
                dh += al;
            }
        }
#pragma unroll
        for (int jb = 0; jb < 8; ++jb) {
            acc[jb] += __shfl_xor(acc[jb], 16, 64);
            acc[jb] += __shfl_xor(acc[jb], 32, 64);
        }
        dh += __shfl_xor(dh, 16, 64);
        dh += __shfl_xor(dh, 32, 64);
        const float inv = 1.f / dh;
#pragma unroll
        for (int jb = 0; jb < 8; ++jb) {
            const float o = acc[jb] * inv + bgv[jb];
            pool[jb] = fmaxf(pool[jb], o > 0.f ? o : 0.f);
        }
    }
    if (sub == 0) {
#pragma unroll
        for (int jb = 0; jb < 8; ++jb) pm[w][cl * 8 + jb] = pool[jb];
    }
    __syncthreads();
    if (w == 0 && sub == 0) {
        const size_t gp = (size_t)gl * kHD;
#pragma unroll
        for (int jb = 0; jb < 8; ++jb) {
            const int c = cl * 8 + jb;
            float vmax = fmaxf(fmaxf(pm[0][c], pm[1][c]), fmaxf(pm[2][c], pm[3][c]));
            atomicMax(pooled + gp + c, __float_as_uint(vmax));
        }
    }
}

// ---------------------------------------------------------------------------
// Kernel 3: LSTM over T=16 + classifier. One block per batch row b.
// ---------------------------------------------------------------------------
__global__ __launch_bounds__(256) void lstm_head(
        const float* __restrict__ pooled,
        const unsigned short* __restrict__ Wih,
        const unsigned short* __restrict__ Whh,
        const unsigned short* __restrict__ bih,
        const unsigned short* __restrict__ bhh,
        const unsigned short* __restrict__ Wclf,
        const unsigned short* __restrict__ bclf,
        const int* __restrict__ flag,
        void* __restrict__ out) {
    const int b = blockIdx.x;
    const int r = threadIdx.x;
    __shared__ float xt[kHD];
    __shared__ float hs[kHL];
    __shared__ float gates[4 * kHL];

    uint32_t wih[64];
    const uint32_t* pw = (const uint32_t*)(Wih + (size_t)r * kHD);
#pragma unroll
    for (int j = 0; j < 64; ++j) wih[j] = pw[j];
    uint32_t whh[32];
    const uint32_t* ph = (const uint32_t*)(Whh + (size_t)r * kHL);
#pragma unroll
    for (int j = 0; j < 32; ++j) whh[j] = ph[j];
    const float bias = bf2f(bih[r]) + bf2f(bhh[r]);

    float c_st = 0.f;
    if (r < kHL) hs[r] = 0.f;
    __syncthreads();

    for (int t = 0; t < kT; ++t) {
        if (r < kHD) xt[r] = pooled[((size_t)b * kT + t) * kHD + r];
        __syncthreads();
        float a0 = 0.f, a1 = 0.f, a2 = 0.f, a3 = 0.f;
#pragma unroll
        for (int j = 0; j < 64; j += 4) {
            uint32_t u0 = wih[j], u1 = wih[j + 1], u2 = wih[j + 2], u3 = wih[j + 3];
            a0 += blo(u0) * xt[2 * j + 0] + __uint_as_float(u0 & 0xffff0000u) * xt[2 * j + 1];
            a1 += blo(u1) * xt[2 * j + 2] + __uint_as_float(u1 & 0xffff0000u) * xt[2 * j + 3];
            a2 += blo(u2) * xt[2 * j + 4] + __uint_as_float(u2 & 0xffff0000u) * xt[2 * j + 5];
            a3 += blo(u3) * xt[2 * j + 6] + __uint_as_float(u3 & 0xffff0000u) * xt[2 * j + 7];
        }
#pragma unroll
        for (int j = 0; j < 32; j += 4) {
            uint32_t u0 = whh[j], u1 = whh[j + 1], u2 = whh[j + 2], u3 = whh[j + 3];
            a0 += blo(u0) * hs[2 * j + 0] + __uint_as_float(u0 & 0xffff0000u) * hs[2 * j + 1];
            a1 += blo(u1) * hs[2 * j + 2] + __uint_as_float(u1 & 0xffff0000u) * hs[2 * j + 3];
            a2 += blo(u2) * hs[2 * j + 4] + __uint_as_float(u2 & 0xffff0000u) * hs[2 * j + 5];
            a3 += blo(u3) * hs[2 * j + 6] + __uint_as_float(u3 & 0xffff0000u) * hs[2 * j + 7];
        }
        gates[r] = bias + (a0 + a1) + (a2 + a3);
        __syncthreads();
        if (r < kHL) {
            const float iv = sigm(gates[r]);
            const float fv = sigm(gates[kHL + r]);
            const float gv = tanhf(gates[2 * kHL + r]);
            const float ov = sigm(gates[3 * kHL + r]);
            c_st = fv * c_st + iv * gv;
            hs[r] = ov * tanhf(c_st);
        }
        __syncthreads();
    }
    if (r < kOUT) {
        float acc = bf2f(bclf[r]);
#pragma unroll
        for (int k = 0; k < kHL; ++k) acc += hs[k] * bf2f(Wclf[r * kHL + k]);
        if (*flag) ((float*)out)[b * kOUT + r] = acc;
        else ((__hip_bfloat16*)out)[b * kOUT + r] = __float2bfloat16(acc);
    }
}

// ---------------------------------------------------------------------------
extern "C" void kernel_launch(void* const* d_in, const int* in_sizes, int n_in,
                              void* d_out, int out_size, void* d_ws, size_t ws_size,
                              hipStream_t stream) {
    const int* ei = (const int*)d_in[1];

    char* ws = (char*)d_ws;
    int*            flag   = (int*)(ws + OFF_FLAG);
    int*            row    = (int*)(ws + OFF_ROW);
    int*            colv   = (int*)(ws + OFF_COL);
    unsigned int*   pooled = (unsigned int*)(ws + OFF_POOL);
    unsigned short* canon  = (unsigned short*)(ws + OFF_CANON);

    unsigned short* cBg   = canon + CX_BG;
    unsigned short* cWih  = canon + CX_WIH;
    unsigned short* cWhh  = canon + CX_WHH;
    unsigned short* cBih  = canon + CX_BIH;
    unsigned short* cBhh  = canon + CX_BHH;
    unsigned short* cWclf = canon + CX_WCLF;
    unsigned short* cBclf = canon + CX_BCLF;

    float*          a_s = (float*)(ws + OFF_AS);
    float*          a_d = (float*)(ws + OFF_AS + (size_t)kG * 16000);
    unsigned short* xp  = (unsigned short*)(ws + OFF_AS + (size_t)kG * 32000);

    ConvArgs ca;
    const int sizes[10] = {2048, 128, 128, 128, 32768, 16384, 256, 256, 512, 8};
    const int which[10] = {2, 3, 4, 5, 6, 7, 8, 9, 10, 11};
    for (int i = 0; i < 10; ++i) {
        ca.src[i] = (const unsigned short*)d_in[which[i]];
        ca.n[i] = sizes[i];
    }

    mega_setup<<<kSetupBlocks + kG * 16, 256, 0, stream>>>(
        d_in[0], ei, ca,
        (const unsigned short*)d_in[2], (const unsigned short*)d_in[3],
        (const unsigned short*)d_in[4],
        flag, row, colv, canon, xp, a_s, a_d, pooled);
    gat_aggregate<<<kG * 50, 256, 0, stream>>>(row, colv, xp, a_s, a_d, cBg, pooled);
    lstm_head<<<kB, 256, 0, stream>>>((const float*)pooled, cWih, cWhh, cBih, cBhh,
                                      cWclf, cBclf, flag, d_out);
}

// Round 9
// 221.326 us; speedup vs baseline: 1.1339x; 1.1339x over previous
//
#include <hip/hip_runtime.h>
#include <hip/hip_bf16.h>
#include <stdint.h>

namespace {
constexpr int kB = 8, kT = 16, kN = 1000, kF = 16;
constexpr int kE = 16000;
constexpr int kH = 4, kHD = 128;
constexpr int kHL = 64, kOUT = 8;
constexpr int kG = kB * kT;
constexpr float kNeg = 0.2f;
constexpr int kNB = 25;                  // aggregate blocks per graph

// Canonical bf16 weights (for lstm_head + bg), element offsets:
constexpr size_t CX_WG   = 0;                       // 2048 (layout only)
constexpr size_t CX_ATS  = CX_WG   + 2048;
constexpr size_t CX_ATD  = CX_ATS  + 128;
constexpr size_t CX_BG   = CX_ATD  + 128;
constexpr size_t CX_WIH  = CX_BG   + 128;
constexpr size_t CX_WHH  = CX_WIH  + 32768;
constexpr size_t CX_BIH  = CX_WHH  + 16384;
constexpr size_t CX_BHH  = CX_BIH  + 256;
constexpr size_t CX_WCLF = CX_BHH  + 256;
constexpr size_t CX_BCLF = CX_WCLF + 512;
constexpr size_t CX_TOTAL = CX_BCLF + 8;

// Workspace byte offsets (256-aligned)
constexpr size_t OFF_FLAG  = 0;
constexpr size_t OFF_ROW   = 256;
constexpr size_t OFF_COL   = 4352;
constexpr size_t OFF_POOL  = 68608;                  // float[kG*kHD] (fallback)
constexpr size_t OFF_CANON = 134400;                 // bf16[CX_TOTAL]
constexpr size_t OFF_AS    = 239872;
// a_s: 128*16000 B, a_d: 128*16000 B, xp(bf16): 128*256000 B
constexpr size_t OFF_PPART = OFF_AS + (size_t)kG * 288000;   // 37,103,872
constexpr size_t PPART_BYTES = (size_t)kG * kNB * kHD * 4;   // 1,638,400

constexpr int kSetupBlocks = 10;   // 0: CSR, 1..8: convert, 9: pooled zero
}

__device__ __forceinline__ float bf2f(unsigned short u) {
    return __uint_as_float(((uint32_t)u) << 16);
}
__device__ __forceinline__ float blo(uint32_t u) { return __uint_as_float(u << 16); }
__device__ __forceinline__ unsigned short f2bf(float f) {
    uint32_t u = __float_as_uint(f);
    uint32_t r = (u + 0x7fff + ((u >> 16) & 1)) >> 16;
    return (unsigned short)r;
}
__device__ __forceinline__ float sigm(float x) { return 1.f / (1.f + __expf(-x)); }

// dtype probe: bf16 N(0,1) shorts are ~100% in exponent band [97,143];
// fp32 viewed as shorts ~59%. Returns 1 if tensors are fp32.
__device__ __forceinline__ int detect_isf(const unsigned short* xs, int t,
                                          int nthr, int* sh_cnt) {
    if (t == 0) *sh_cnt = 0;
    __syncthreads();
    int loc = 0;
    for (int i = t; i < 2048; i += nthr) {
        unsigned short u = xs[i];
        int ex = (u >> 7) & 0xff;
        if (u == 0 || (ex >= 97 && ex <= 143)) loc++;
    }
    atomicAdd(sh_cnt, loc);
    __syncthreads();
    return (*sh_cnt >= (2048 * 8) / 10) ? 0 : 1;
}

struct ConvArgs {
    const unsigned short* src[10];
    int n[10];
};

// ---------------------------------------------------------------------------
// Kernel 1 (mega-setup, 10+2048 blocks x 256):
//  block 0:    CSR build (dst-sorted edges), wave-scan
//  blocks 1-8: convert weights to canonical bf16 (8-way split)
//  block 9:    zero pooled (used by atomic fallback only; harmless otherwise)
//  blocks 10+: xp = x @ W_gat (packed-uint stores) + a_s/a_d via folded
//              weights (lane-rotated d-loop: conflict-free). Graph-major XCD
//              swizzle (matches gat_aggregate -> L2 temporal locality).
// ---------------------------------------------------------------------------
__global__ __launch_bounds__(256) void mega_setup(
        const void* __restrict__ xraw, const int* __restrict__ ei,
        ConvArgs ca,
        const unsigned short* __restrict__ WgR,
        const unsigned short* __restrict__ atsR,
        const unsigned short* __restrict__ atdR,
        int* __restrict__ flag, int* __restrict__ row, int* __restrict__ col,
        unsigned short* __restrict__ canon,
        unsigned short* __restrict__ xp_all,
        float* __restrict__ as_all, float* __restrict__ ad_all,
        unsigned int* __restrict__ pooled) {
    const int t = threadIdx.x;
    const unsigned short* xs = (const unsigned short*)xraw;

    if (blockIdx.x == 0) {
        // ================= CSR build =================
        __shared__ int cnt[1024];
        __shared__ int wtot[4];
        const int lane = t & 63, w = t >> 6;
        for (int i = t; i < 1024; i += 256) cnt[i] = 0;
        __syncthreads();
        const int* dst = ei + kE;
        for (int e = t; e < kE; e += 256) atomicAdd(&cnt[dst[e]], 1);
        __syncthreads();
        const int n0 = 4 * t;
        int c0 = cnt[n0], c1 = cnt[n0 + 1], c2 = cnt[n0 + 2], c3 = cnt[n0 + 3];
        int s0 = c0, s1 = s0 + c1, s2 = s1 + c2, s3 = s2 + c3;
        int tot = s3;
#pragma unroll
        for (int sft = 1; sft < 64; sft <<= 1) {
            int v = __shfl_up(tot, sft, 64);
            if (lane >= sft) tot += v;
        }
        if (lane == 63) wtot[w] = tot;
        __syncthreads();
        int wexcl = 0;
        for (int j = 0; j < w; ++j) wexcl += wtot[j];
        const int excl = wexcl + tot - s3;
        if (t == 0) row[0] = 0;
        if (n0 < kN) {
            row[n0 + 1] = excl + s0;
            row[n0 + 2] = excl + s1;
            row[n0 + 3] = excl + s2;
            row[n0 + 4] = excl + s3;
        }
        __syncthreads();
        cnt[n0] = excl; cnt[n0 + 1] = excl + s0;
        cnt[n0 + 2] = excl + s1; cnt[n0 + 3] = excl + s2;
        __syncthreads();
        for (int e = t; e < kE; e += 256) {
            int d0 = dst[e];
            int pos = atomicAdd(&cnt[d0], 1);
            col[pos] = ei[e];
        }
    } else if (blockIdx.x <= 8) {
        // ================= weight conversion (8-way split) =================
        __shared__ int dcnt;
        const int isf = detect_isf(xs, t, 256, &dcnt);
        if (blockIdx.x == 1 && t == 0) *flag = isf;
        const int gid = (int)(blockIdx.x - 1) * 256 + t;   // 0..2047
        size_t base = 0;
        for (int s = 0; s < 10; ++s) {
            const int n = ca.n[s];
            if (isf) {
                const float* fp = (const float*)ca.src[s];
                for (int i = gid; i < n; i += 2048) canon[base + i] = f2bf(fp[i]);
            } else {
                const unsigned short* sp = ca.src[s];
                for (int i = gid; i < n; i += 2048) canon[base + i] = sp[i];
            }
            base += (size_t)n;
        }
    } else if (blockIdx.x == 9) {
        for (int i = t; i < kG * kHD; i += 256) pooled[i] = 0u;
    } else {
        // ================= precompute tile =================
        __shared__ int dcnt;
        __shared__ float Wl[kF * kHD];
        __shared__ float asl[kHD], adl[kHD];
        __shared__ float xr[64][20];        // stride 20: conflict-free + aligned
        __shared__ float ws2[2][4][16];     // folded att weights [src/dst][h][f]
        const int isf = detect_isf(xs, t, 256, &dcnt);
        // graph-major XCD swizzle: XCD v handles graphs v, v+8, ... sequentially
        const int i0 = blockIdx.x - kSetupBlocks;
        const int v = i0 & 7;
        const int jj = i0 >> 3;             // 0..255
        const int gl = v + 8 * (jj >> 4);
        const int nb = jj & 15;
        if (isf) {
            const float* wf = (const float*)WgR;
            for (int i = t; i < kF * kHD; i += 256) Wl[i] = wf[i];
            if (t < kHD) asl[t] = ((const float*)atsR)[t];
            else if (t < 2 * kHD) adl[t - kHD] = ((const float*)atdR)[t - kHD];
        } else {
            for (int i = t; i < kF * kHD; i += 256) Wl[i] = bf2f(WgR[i]);
            if (t < kHD) asl[t] = bf2f(atsR[t]);
            else if (t < 2 * kHD) adl[t - kHD] = bf2f(atdR[t - kHD]);
        }
        const int n0 = nb * 64;
        const int nn = min(64, kN - n0);
        const size_t xbase = (size_t)gl * kN * kF + (size_t)n0 * kF;
        if (isf) {
            const float* xf = (const float*)xraw;
            for (int i = t; i < nn * kF; i += 256) xr[i >> 4][i & 15] = xf[xbase + i];
        } else {
            for (int i = t; i < nn * kF; i += 256) xr[i >> 4][i & 15] = bf2f(xs[xbase + i]);
        }
        __syncthreads();

        // folded weights ws2[sd][h][f] = sum_d Wl[f][h*32+d]*att[h*32+d];
        // d-loop rotated by lane -> banks spread, 2-way max (free).
        if (t < 128) {
            const int sd = t >> 6, h = (t >> 4) & 3, f = t & 15;
            const float* att = sd ? adl : asl;
            const int d0r = t & 31;
            float acc = 0.f;
#pragma unroll
            for (int i = 0; i < 32; ++i) {
                const int d = (d0r + i) & 31;
                acc += Wl[f * kHD + h * 32 + d] * att[h * 32 + d];
            }
            ws2[sd][h][f] = acc;
        }

        // xp tile: wave q owns node ln=q,q+4,..; lane p owns channel pair 2p.
        // Packed uint store: 4 B/lane coalesced (256 B per wave-store).
        uint32_t* xp32 = (uint32_t*)(xp_all + (size_t)gl * kN * kHD);
        {
            const int p = t & 63;
            const int q = t >> 6;
            const int c0 = 2 * p;
            float wA[kF], wB[kF];
#pragma unroll
            for (int f = 0; f < kF; ++f) {
                wA[f] = Wl[f * kHD + c0];
                wB[f] = Wl[f * kHD + c0 + 1];
            }
            for (int ln = q; ln < nn; ln += 4) {
                const float4* xrv = (const float4*)xr[ln];
                const float4 x0 = xrv[0], x1 = xrv[1], x2 = xrv[2], x3 = xrv[3];
                float vA = x0.x * wA[0]  + x0.y * wA[1]  + x0.z * wA[2]  + x0.w * wA[3]
                         + x1.x * wA[4]  + x1.y * wA[5]  + x1.z * wA[6]  + x1.w * wA[7]
                         + x2.x * wA[8]  + x2.y * wA[9]  + x2.z * wA[10] + x2.w * wA[11]
                         + x3.x * wA[12] + x3.y * wA[13] + x3.z * wA[14] + x3.w * wA[15];
                float vB = x0.x * wB[0]  + x0.y * wB[1]  + x0.z * wB[2]  + x0.w * wB[3]
                         + x1.x * wB[4]  + x1.y * wB[5]  + x1.z * wB[6]  + x1.w * wB[7]
                         + x2.x * wB[8]  + x2.y * wB[9]  + x2.z * wB[10] + x2.w * wB[11]
                         + x3.x * wB[12] + x3.y * wB[13] + x3.z * wB[14] + x3.w * wB[15];
                const uint32_t pk = (uint32_t)f2bf(vA) | ((uint32_t)f2bf(vB) << 16);
                xp32[(size_t)(n0 + ln) * 64 + p] = pk;
            }
        }
        __syncthreads();

        // a_s/a_d: thread t -> (node n=t>>2, head h=t&3); 16-MAC dots via ws2
        {
            const int n = t >> 2, h = t & 3;
            if (n < nn) {
                const float* xv = xr[n];
                const float* wsv = ws2[0][h];
                const float* wdv = ws2[1][h];
                float accS = 0.f, accD = 0.f;
#pragma unroll
                for (int f = 0; f < kF; ++f) {
                    const float xf = xv[f];
                    accS += xf * wsv[f];
                    accD += xf * wdv[f];
                }
                as_all[((size_t)gl * kN + n0 + n) * kH + h] = accS;
                ad_all[((size_t)gl * kN + n0 + n) * kH + h] = accD;
            }
        }
    }
}

// ---------------------------------------------------------------------------
// Kernel 2: GAT edge-softmax aggregation + relu + max-pool.
// One block = 40 nodes of ONE graph (10 iters x 4 waves; R7 operating point —
// R8 showed per-block overhead dominates, fewer/larger blocks win).
// Graph-major XCD swizzle (matches mega_setup -> L2 temporal locality).
// Epilogue: plain per-block partial-max stores if ws has room (use_part=1),
// else atomicMax fallback into pooled.
// ---------------------------------------------------------------------------
__global__ __launch_bounds__(256) void gat_aggregate(
        const int* __restrict__ row, const int* __restrict__ col,
        const unsigned short* __restrict__ xp,
        const float* __restrict__ a_s, const float* __restrict__ a_d,
        const unsigned short* __restrict__ bg,
        unsigned int* __restrict__ pooled,
        float* __restrict__ part, int use_part) {
    __shared__ int   col_lds[4][64];
    __shared__ float p_lds[4][4][72];
    __shared__ float pm[4][kHD];

    const int w = threadIdx.x >> 6;
    const int lane = threadIdx.x & 63;
    const int sub = lane >> 4;          // edge subgroup 0..3
    const int cl = lane & 15;           // channels cl*8 .. cl*8+7
    const int hh = cl >> 2;
    const int xcd = blockIdx.x & 7;
    const int j = blockIdx.x >> 3;      // 0..399
    const int gl = xcd + 8 * (j / kNB); // graph-major within XCD
    const int blk = j % kNB;            // 0..24
    const size_t gn = (size_t)gl * kN;
    const char* xpcl = (const char*)(xp + gn * kHD) + cl * 16;
    const float4* as4 = (const float4*)a_s + gn;
    const float4* ad4 = (const float4*)a_d + gn;
    const uint32_t* bg32 = (const uint32_t*)bg;
    float bgv[8];
#pragma unroll
    for (int jb = 0; jb < 4; ++jb) {
        uint32_t u = bg32[cl * 4 + jb];
        bgv[2 * jb] = blo(u);
        bgv[2 * jb + 1] = __uint_as_float(u & 0xffff0000u);
    }
    float pool[8];
#pragma unroll
    for (int jb = 0; jb < 8; ++jb) pool[jb] = 0.f;

    for (int it = 0; it < 10; ++it) {
        const int n = blk * 40 + it * 4 + w;
        const int r0 = row[n];
        const int deg = row[n + 1] - r0;
        const int E = deg + 1;          // + self loop (index deg)
        const float4 dv = ad4[n];
        float acc[8];
#pragma unroll
        for (int jb = 0; jb < 8; ++jb) acc[jb] = 0.f;
        float dh = 0.f;

        for (int base = 0; base < E; base += 64) {
            const int cnt = min(64, E - base);
            const int cntP = (cnt + 3) & ~3;
            // ---- phase 1: lanes = edges (pad lanes get alpha 0) ----
            if (lane < cntP) {
                const int eg = base + lane;
                const bool act = lane < cnt;
                const int s = (act && eg < deg) ? col[r0 + eg] : n;
                float p0 = 0.f, p1 = 0.f, p2 = 0.f, p3 = 0.f;
                if (act) {
                    const float4 av = as4[s];
                    float t0 = av.x + dv.x, t1 = av.y + dv.y;
                    float t2 = av.z + dv.z, t3 = av.w + dv.w;
                    t0 = t0 > 0.f ? t0 : kNeg * t0;
                    t1 = t1 > 0.f ? t1 : kNeg * t1;
                    t2 = t2 > 0.f ? t2 : kNeg * t2;
                    t3 = t3 > 0.f ? t3 : kNeg * t3;
                    p0 = __expf(t0); p1 = __expf(t1);
                    p2 = __expf(t2); p3 = __expf(t3);
                }
                col_lds[w][lane] = s << 8;          // xp row byte offset
                p_lds[w][0][lane] = p0;
                p_lds[w][1][lane] = p1;
                p_lds[w][2][lane] = p2;
                p_lds[w][3][lane] = p3;
            }
            // wave-synchronous LDS use; branch-free inner loop
            for (int e0 = 0; e0 < cntP; e0 += 4) {
                const int e = e0 + sub;
                const int off = col_lds[w][e];
                const float al = p_lds[w][hh][e];
                const uint4 u = *(const uint4*)(xpcl + off);
                acc[0] += al * blo(u.x); acc[1] += al * __uint_as_float(u.x);
                acc[2] += al * blo(u.y); acc[3] += al * __uint_as_float(u.y);
                acc[4] += al * blo(u.z); acc[5] += al * __uint_as_float(u.z);
                acc[6] += al * blo(u.w); acc[7] += al * __uint_as_float(u.w);
                dh += al;
            }
        }
#pragma unroll
        for (int jb = 0; jb < 8; ++jb) {
            acc[jb] += __shfl_xor(acc[jb], 16, 64);
            acc[jb] += __shfl_xor(acc[jb], 32, 64);
        }
        dh += __shfl_xor(dh, 16, 64);
        dh += __shfl_xor(dh, 32, 64);
        const float inv = 1.f / dh;
#pragma unroll
        for (int jb = 0; jb < 8; ++jb) {
            const float o = acc[jb] * inv + bgv[jb];
            pool[jb] = fmaxf(pool[jb], o > 0.f ? o : 0.f);
        }
    }
    if (sub == 0) {
#pragma unroll
        for (int jb = 0; jb < 8; ++jb) pm[w][cl * 8 + jb] = pool[jb];
    }
    __syncthreads();
    if (w == 0 && sub == 0) {
        if (use_part) {
            float* dst = part + ((size_t)gl * kNB + blk) * kHD;
#pragma unroll
            for (int jb = 0; jb < 8; ++jb) {
                const int c = cl * 8 + jb;
                dst[c] = fmaxf(fmaxf(pm[0][c], pm[1][c]), fmaxf(pm[2][c], pm[3][c]));
            }
        } else {
            const size_t gp = (size_t)gl * kHD;
#pragma unroll
            for (int jb = 0; jb < 8; ++jb) {
                const int c = cl * 8 + jb;
                float vmax = fmaxf(fmaxf(pm[0][c], pm[1][c]), fmaxf(pm[2][c], pm[3][c]));
                atomicMax(pooled + gp + c, __float_as_uint(vmax));
            }
        }
    }
}

// ---------------------------------------------------------------------------
// Kernel 3: LSTM over T=16 + classifier. One block per batch row b.
// xt load folds the kNB-way partial-max reduce when use_part=1.
// ---------------------------------------------------------------------------
__global__ __launch_bounds__(256) void lstm_head(
        const float* __restrict__ pooled, const float* __restrict__ part,
        int use_part,
        const unsigned short* __restrict__ Wih,
        const unsigned short* __restrict__ Whh,
        const unsigned short* __restrict__ bih,
        const unsigned short* __restrict__ bhh,
        const unsigned short* __restrict__ Wclf,
        const unsigned short* __restrict__ bclf,
        const int* __restrict__ flag,
        void* __restrict__ out) {
    const int b = blockIdx.x;
    const int r = threadIdx.x;
    __shared__ float xt[kHD];
    __shared__ float hs[kHL];
    __shared__ float gates[4 * kHL];

    uint32_t wih[64];
    const uint32_t* pw = (const uint32_t*)(Wih + (size_t)r * kHD);
#pragma unroll
    for (int j = 0; j < 64; ++j) wih[j] = pw[j];
    uint32_t whh[32];
    const uint32_t* ph = (const uint32_t*)(Whh + (size_t)r * kHL);
#pragma unroll
    for (int j = 0; j < 32; ++j) whh[j] = ph[j];
    const float bias = bf2f(bih[r]) + bf2f(bhh[r]);

    float c_st = 0.f;
    if (r < kHL) hs[r] = 0.f;
    __syncthreads();

    for (int t = 0; t < kT; ++t) {
        const size_t g = (size_t)b * kT + t;
        if (r < kHD) {
            if (use_part) {
                const float* ps = part + g * kNB * kHD + r;
                float v = ps[0];
#pragma unroll
                for (int k = 1; k < kNB; ++k) v = fmaxf(v, ps[(size_t)k * kHD]);
                xt[r] = v;
            } else {
                xt[r] = pooled[g * kHD + r];
            }
        }
        __syncthreads();
        float a0 = 0.f, a1 = 0.f, a2 = 0.f, a3 = 0.f;
#pragma unroll
        for (int j = 0; j < 64; j += 4) {
            uint32_t u0 = wih[j], u1 = wih[j + 1], u2 = wih[j + 2], u3 = wih[j + 3];
            a0 += blo(u0) * xt[2 * j + 0] + __uint_as_float(u0 & 0xffff0000u) * xt[2 * j + 1];
            a1 += blo(u1) * xt[2 * j + 2] + __uint_as_float(u1 & 0xffff0000u) * xt[2 * j + 3];
            a2 += blo(u2) * xt[2 * j + 4] + __uint_as_float(u2 & 0xffff0000u) * xt[2 * j + 5];
            a3 += blo(u3) * xt[2 * j + 6] + __uint_as_float(u3 & 0xffff0000u) * xt[2 * j + 7];
        }
#pragma unroll
        for (int j = 0; j < 32; j += 4) {
            uint32_t u0 = whh[j], u1 = whh[j + 1], u2 = whh[j + 2], u3 = whh[j + 3];
            a0 += blo(u0) * hs[2 * j + 0] + __uint_as_float(u0 & 0xffff0000u) * hs[2 * j + 1];
            a1 += blo(u1) * hs[2 * j + 2] + __uint_as_float(u1 & 0xffff0000u) * hs[2 * j + 3];
            a2 += blo(u2) * hs[2 * j + 4] + __uint_as_float(u2 & 0xffff0000u) * hs[2 * j + 5];
            a3 += blo(u3) * hs[2 * j + 6] + __uint_as_float(u3 & 0xffff0000u) * hs[2 * j + 7];
        }
        gates[r] = bias + (a0 + a1) + (a2 + a3);
        __syncthreads();
        if (r < kHL) {
            const float iv = sigm(gates[r]);
            const float fv = sigm(gates[kHL + r]);
            const float gv = tanhf(gates[2 * kHL + r]);
            const float ov = sigm(gates[3 * kHL + r]);
            c_st = fv * c_st + iv * gv;
            hs[r] = ov * tanhf(c_st);
        }
        __syncthreads();
    }
    if (r < kOUT) {
        float acc = bf2f(bclf[r]);
#pragma unroll
        for (int k = 0; k < kHL; ++k) acc += hs[k] * bf2f(Wclf[r * kHL + k]);
        if (*flag) ((float*)out)[b * kOUT + r] = acc;
        else ((__hip_bfloat16*)out)[b * kOUT + r] = __float2bfloat16(acc);
    }
}

// ---------------------------------------------------------------------------
extern "C" void kernel_launch(void* const* d_in, const int* in_sizes, int n_in,
                              void* d_out, int out_size, void* d_ws, size_t ws_size,
                              hipStream_t stream) {
    const int* ei = (const int*)d_in[1];

    char* ws = (char*)d_ws;
    int*            flag   = (int*)(ws + OFF_FLAG);
    int*            row    = (int*)(ws + OFF_ROW);
    int*            colv   = (int*)(ws + OFF_COL);
    unsigned int*   pooled = (unsigned int*)(ws + OFF_POOL);
    unsigned short* canon  = (unsigned short*)(ws + OFF_CANON);

    unsigned short* cBg   = canon + CX_BG;
    unsigned short* cWih  = canon + CX_WIH;
    unsigned short* cWhh  = canon + CX_WHH;
    unsigned short* cBih  = canon + CX_BIH;
    unsigned short* cBhh  = canon + CX_BHH;
    unsigned short* cWclf = canon + CX_WCLF;
    unsigned short* cBclf = canon + CX_BCLF;

    float*          a_s = (float*)(ws + OFF_AS);
    float*          a_d = (float*)(ws + OFF_AS + (size_t)kG * 16000);
    unsigned short* xp  = (unsigned short*)(ws + OFF_AS + (size_t)kG * 32000);

    // ws_size is fixed per session -> use_part constant -> graph-capture safe
    const int use_part = (ws_size >= OFF_PPART + PPART_BYTES) ? 1 : 0;
    float* part = (float*)(ws + OFF_PPART);

    ConvArgs ca;
    const int sizes[10] = {2048, 128, 128, 128, 32768, 16384, 256, 256, 512, 8};
    const int which[10] = {2, 3, 4, 5, 6, 7, 8, 9, 10, 11};
    for (int i = 0; i < 10; ++i) {
        ca.src[i] = (const unsigned short*)d_in[which[i]];
        ca.n[i] = sizes[i];
    }

    mega_setup<<<kSetupBlocks + kG * 16, 256, 0, stream>>>(
        d_in[0], ei, ca,
        (const unsigned short*)d_in[2], (const unsigned short*)d_in[3],
        (const unsigned short*)d_in[4],
        flag, row, colv, canon, xp, a_s, a_d, pooled);
    gat_aggregate<<<kG * kNB, 256, 0, stream>>>(row, colv, xp, a_s, a_d, cBg,
                                                pooled, part, use_part);
    lstm_head<<<kB, 256, 0, stream>>>((const float*)pooled, part, use_part,
                                      cWih, cWhh, cBih, cBhh,
                                      cWclf, cBclf, flag, d_out);
}